// Round 6
// baseline (74.361 us; speedup 1.0000x reference)
//
#include <hip/hip_runtime.h>
#include <hip/hip_bf16.h>

#define NDIGIT 10
#define DIM_IN 256
#define DIM_OUT 784
#define BATCH 16384
#define BM 64
#define BN 112
#define NCB 7
#define MAX_MT (BATCH / BM + NDIGIT)        // 266 (fallback)
#define GEMM_BLOCKS (MAX_MT * NCB)          // 1862 (fallback)
#define MAX_CHUNKS (BATCH / 256 + NDIGIT)   // 74
#define G6_BLOCKS (MAX_CHUNKS * NCB)        // 518
#define HBYTES 28672                        // one K-half of W panel: 112 x 128 x 2B

// ws layout:
//  ints [0..10]    bucket row offsets[11]
//  ints [12..22]   64-row tile offsets[11]   (fallback gemm4)
//  ints [24]       total 64-row tiles        (fallback gemm4)
//  ints [26..36]   256-row chunk offsets[11] (gemm6)
//  ints [38]       total chunks              (gemm6)
//  ints [64 + j*16 + g]  per-hist-block partial counts (j<32, g<10)
//  ints [1024..17407]    idx[16384]
//  byte 69632..           W bf16 (2,007,040 shorts)
//  byte 4,083,712..       thsort bf16 (16384 x 256, sorted by label)
#define WS_IDX 1024
#define WS_WBF_BYTES 69632
#define WS_TH_BYTES (WS_WBF_BYTES + 2007040 * 2)          // 4,083,712
#define WS_NEED_NEW (WS_TH_BYTES + BATCH * DIM_IN * 2)    // 12,472,320

typedef __attribute__((ext_vector_type(4))) float f32x4;
typedef __attribute__((ext_vector_type(8))) short bf16x8;

__device__ __forceinline__ short f2bf(float f) {
    union { float f; unsigned u; } c; c.f = f;
    unsigned u = c.u;
    u += 0x7fffu + ((u >> 16) & 1u);   // RNE
    return (short)(u >> 16);
}

__device__ __forceinline__ void gload16(const void* gp, void* lp) {
    __builtin_amdgcn_global_load_lds(
        (const __attribute__((address_space(1))) void*)gp,
        (__attribute__((address_space(3))) void*)lp, 16, 0, 0);
}

// blocks [0,980): convert megaW f32 -> bf16; blocks [980,1012): label histograms
__global__ void prep_k(const float* __restrict__ megaW,
                       const int* __restrict__ label,
                       int* __restrict__ wsi,
                       short* __restrict__ wbf) {
    int b = blockIdx.x, t = threadIdx.x;
    if (b < 980) {
        int base = b * 2048 + t * 8;
        f32x4 v0 = *(const f32x4*)(megaW + base);
        f32x4 v1 = *(const f32x4*)(megaW + base + 4);
        bf16x8 o;
        o[0] = f2bf(v0[0]); o[1] = f2bf(v0[1]); o[2] = f2bf(v0[2]); o[3] = f2bf(v0[3]);
        o[4] = f2bf(v1[0]); o[5] = f2bf(v1[1]); o[6] = f2bf(v1[2]); o[7] = f2bf(v1[3]);
        *(bf16x8*)(wbf + base) = o;
    } else {
        __shared__ int h[NDIGIT];
        int j = b - 980;
        if (t < NDIGIT) h[t] = 0;
        __syncthreads();
        int i0 = j * 512;
        atomicAdd(&h[label[i0 + t]], 1);
        atomicAdd(&h[label[i0 + 256 + t]], 1);
        __syncthreads();
        if (t < NDIGIT) wsi[64 + j * 16 + t] = h[t];
    }
}

// 32 blocks x 512 threads; block j owns rows [j*512, j*512+512)
__global__ void scatter2_k(const int* __restrict__ label, int* __restrict__ wsi) {
    __shared__ int tot[NDIGIT], bef[NDIGIT], base[NDIGIT + 1], cur[NDIGIT];
    int j = blockIdx.x, t = threadIdx.x;
    if (t < NDIGIT) {
        int s = 0, sb = 0;
        for (int jj = 0; jj < 32; ++jj) {
            int v = wsi[64 + jj * 16 + t];
            s += v;
            if (jj < j) sb += v;
        }
        tot[t] = s; bef[t] = sb;
    }
    __syncthreads();
    if (t == 0) {
        int off = 0;
        for (int g = 0; g < NDIGIT; ++g) { base[g] = off; off += tot[g]; }
        base[NDIGIT] = off;
    }
    __syncthreads();
    if (t < NDIGIT) cur[t] = base[t] + bef[t];
    __syncthreads();
    int i = j * 512 + t;
    int g = label[i];
    int r = atomicAdd(&cur[g], 1);
    wsi[WS_IDX + r] = i;
    if (j == 0 && t == 0) {
        int off = 0, toff = 0, choff = 0;
        for (int g2 = 0; g2 < NDIGIT; ++g2) {
            wsi[g2] = off; wsi[12 + g2] = toff; wsi[26 + g2] = choff;
            off += tot[g2];
            toff += (tot[g2] + BM - 1) / BM;
            choff += (tot[g2] + 255) / 256;
        }
        wsi[10] = off; wsi[22] = toff; wsi[24] = toff;
        wsi[36] = choff; wsi[38] = choff;
    }
}

// gather theta rows into sorted order, converted to bf16
__global__ void gth_k(const float* __restrict__ theta,
                      const int* __restrict__ wsi,
                      short* __restrict__ thsort) {
    int gid = blockIdx.x * 256 + threadIdx.x;
    int r = gid >> 5;
    int c8 = (gid & 31) << 3;
    int src = wsi[WS_IDX + r];
    const float* p = theta + (size_t)src * DIM_IN + c8;
    f32x4 v0 = *(const f32x4*)p;
    f32x4 v1 = *(const f32x4*)(p + 4);
    bf16x8 o;
    o[0] = f2bf(v0[0]); o[1] = f2bf(v0[1]); o[2] = f2bf(v0[2]); o[3] = f2bf(v0[3]);
    o[4] = f2bf(v1[0]); o[5] = f2bf(v1[1]); o[6] = f2bf(v1[2]); o[7] = f2bf(v1[3]);
    *(bf16x8*)(thsort + (size_t)r * DIM_IN + c8) = o;
}

// ===================== gemm6: 256-row chunk per block =====================

#define LOADA(A, T) do {                                                       \
    int arow_ = start + row0 + (T) * 64 + wv * 16 + r16;                       \
    int amax_ = start + cnt - 1;                                               \
    if (arow_ > amax_) arow_ = amax_;                                          \
    const short* Ar_ = thsort + (size_t)arow_ * DIM_IN + kg * 8;               \
    _Pragma("unroll")                                                          \
    for (int ks = 0; ks < 8; ++ks) (A)[ks] = *(const bf16x8*)(Ar_ + ks * 32);  \
} while (0)

#define LOADO(O, T) do {                                                       \
    const int* idxl_ = wsi + WS_IDX + start + row0 + (T) * 64;                 \
    _Pragma("unroll")                                                          \
    for (int j = 0; j < 4; ++j) {                                              \
        int rl_ = (T) * 64 + rb + j;                                           \
        (O)[j] = (rl_ < cnt - row0) ? idxl_[rb + j] : -1;                      \
    }                                                                          \
} while (0)

#define CMPH(H, A, BUF) do {                                                   \
    _Pragma("unroll")                                                          \
    for (int ksl = 0; ksl < 4; ++ksl) {                                        \
        _Pragma("unroll")                                                      \
        for (int ns = 0; ns < NCB; ++ns) {                                     \
            int n_ = ns * 16 + r16;                                            \
            int byte_ = (n_ << 8) + (ksl << 6) + (kg << 4);                    \
            byte_ ^= (n_ & 7) << 4;                                            \
            bf16x8 bfr_ = *(const bf16x8*)((const char*)(BUF) + byte_);        \
            acc[ns] = __builtin_amdgcn_mfma_f32_16x16x32_bf16(                 \
                (A)[(H) * 4 + ksl], bfr_, acc[ns], 0, 0, 0);                   \
        }                                                                      \
    }                                                                          \
} while (0)

#define ZACC() do {                                                            \
    _Pragma("unroll")                                                          \
    for (int ns = 0; ns < NCB; ++ns) acc[ns] = (f32x4){0.f, 0.f, 0.f, 0.f};   \
} while (0)

#define EPI(O) do {                                                            \
    _Pragma("unroll")                                                          \
    for (int ns = 0; ns < NCB; ++ns) {                                         \
        int nloc_ = ns * 16 + r16;                                             \
        _Pragma("unroll")                                                      \
        for (int j = 0; j < 4; ++j) {                                          \
            if ((O)[j] >= 0) {                                                 \
                float x_ = acc[ns][j] + biasv[ns];                             \
                out[(size_t)(O)[j] * DIM_OUT + cb * BN + nloc_] =              \
                    1.0f / (1.0f + __expf(-x_));                               \
            }                                                                  \
        }                                                                      \
    }                                                                          \
} while (0)

#define STAGEH(H, BUF) do {                                                    \
    _Pragma("unroll")                                                          \
    for (int it = 0; it < 7; ++it) {                                           \
        int lbyte_ = (it * 256 + tid) << 4;                                    \
        int L_ = lbyte_ ^ (((lbyte_ >> 8) & 7) << 4);                          \
        int src_ = ((L_ >> 8) << 9) + (L_ & 255) + (H) * 256;                  \
        gload16(Wcb + src_, (char*)(BUF) + lbyte_);                            \
    }                                                                          \
} while (0)

__launch_bounds__(256, 2)
__global__ void moe_gemm6_k(const short* __restrict__ thsort,
                            const float* __restrict__ megab,
                            const int* __restrict__ wsi,
                            const short* __restrict__ wbf,
                            float* __restrict__ out) {
    __shared__ char Bs0[HBYTES];   // k 0..127 of the 112-row panel
    __shared__ char Bs1[HBYTES];   // k 128..255

    int Bid = blockIdx.x;
    const int q8 = G6_BLOCKS / 8, r8 = G6_BLOCKS % 8;   // 64, 6
    int xcd = Bid & 7, slot = Bid >> 3;
    int w = (xcd < r8 ? xcd * (q8 + 1) : r8 * (q8 + 1) + (xcd - r8) * q8) + slot;
    int ct = w / NCB, cb = w % NCB;

    int ctotal = wsi[38];
    if (ct >= ctotal) return;           // uniform exit before barriers

    int tid = threadIdx.x;
    int wv = tid >> 6, l = tid & 63, r16 = l & 15, kg = l >> 4;
    int rb = wv * 16 + kg * 4;

    // expert mapping via one ballot (no dependent-load walk)
    int coff = (l < 11) ? wsi[26 + l] : 0x7fffffff;
    int boff = (l < 11) ? wsi[l] : 0;
    unsigned long long m = __ballot(ct >= coff);   // lanes 0..g set
    int g = __popcll(m) - 1;
    int lc    = ct - __shfl(coff, g);
    int start = __shfl(boff, g);
    int cnt   = __shfl(boff, g + 1) - start;
    int row0  = lc * 256;

    const char* Wcb = (const char*)(wbf + ((size_t)g * DIM_OUT + (size_t)cb * BN) * DIM_IN);

    // ---- prologue loads (oldest vmem: forced complete by the counted wait)
    bf16x8 a0[8], a1[8];
    int or0[4], or1[4];
    LOADA(a0, 0);
    LOADO(or0, 0);
    float biasv[NCB];
    {
        const float* bg = megab + (size_t)g * DIM_OUT + cb * BN;
#pragma unroll
        for (int ns = 0; ns < NCB; ++ns) biasv[ns] = bg[ns * 16 + r16];
    }

    // ---- stage both K-halves (7+7 gload_lds)
    STAGEH(0, Bs0);
    STAGEH(1, Bs1);

    f32x4 acc[NCB];
    ZACC();

    asm volatile("s_waitcnt vmcnt(7)" ::: "memory");   // h0 + prologue done, h1 in flight
    __builtin_amdgcn_s_barrier();
    __builtin_amdgcn_sched_barrier(0);

    CMPH(0, a0, Bs0);                  // tile 0, k 0..127 (overlaps h1 arrival)

    asm volatile("s_waitcnt vmcnt(0)" ::: "memory");   // h1 landed
    __builtin_amdgcn_s_barrier();
    __builtin_amdgcn_sched_barrier(0);

    // ---- barrier-free steady state: per-wave pipelined 4-tile loop
    // tile 0 finish
    LOADA(a1, 1); LOADO(or1, 1);       // prefetch t=1 under compute
    CMPH(1, a0, Bs1);
    EPI(or0);

    // tile 1
    ZACC();
    LOADA(a0, 2); LOADO(or0, 2);
    CMPH(0, a1, Bs0);
    CMPH(1, a1, Bs1);
    EPI(or1);

    // tile 2
    ZACC();
    LOADA(a1, 3); LOADO(or1, 3);
    CMPH(0, a0, Bs0);
    CMPH(1, a0, Bs1);
    EPI(or0);

    // tile 3
    ZACC();
    CMPH(0, a1, Bs0);
    CMPH(1, a1, Bs1);
    EPI(or1);
}

// =============== fallback (round-4 path) ===============
__launch_bounds__(256, 4)
__global__ void moe_gemm4_k(const float* __restrict__ theta,
                            const float* __restrict__ megab,
                            const int* __restrict__ wsi,
                            const short* __restrict__ wbf,
                            float* __restrict__ out) {
    __shared__ short Bsf[BN * 128];
    int Bid = blockIdx.x;
    const int q8 = GEMM_BLOCKS / 8, r8 = GEMM_BLOCKS % 8;
    int xcd = Bid & 7, slot = Bid >> 3;
    int w = (xcd < r8 ? xcd * (q8 + 1) : r8 * (q8 + 1) + (xcd - r8) * q8) + slot;
    int mt = w / NCB, cb = w % NCB;
    int total = wsi[24];
    if (mt >= total) return;
    int g = 0;
    while (mt >= wsi[12 + g + 1]) ++g;
    int lt    = mt - wsi[12 + g];
    int start = wsi[g];
    int cnt   = wsi[g + 1] - start;
    int row0  = lt * BM;
    int rc    = min(BM, cnt - row0);
    int tid = threadIdx.x;
    int wv = tid >> 6, l = tid & 63, r16 = l & 15, kg = l >> 4;
    const char* Wcb = (const char*)(wbf + ((size_t)g * DIM_OUT + (size_t)cb * BN) * DIM_IN);
#pragma unroll
    for (int it = 0; it < 7; ++it) {
        int lbyte = (it * 256 + tid) << 4;
        int L = lbyte ^ (((lbyte >> 8) & 7) << 4);
        int srcoff = ((L >> 8) << 9) + (L & 255);
        gload16(Wcb + srcoff, (char*)Bsf + lbyte);
    }
    const int* idxlist = wsi + WS_IDX + start + row0;
    int mloc = wv * 16 + r16;
    int asrc = (mloc < rc) ? idxlist[mloc] : idxlist[0];
    const float* Arow = theta + (size_t)asrc * DIM_IN;
    bf16x8 a[8];
#pragma unroll
    for (int ks = 0; ks < 8; ++ks) {
        int k0 = ks * 32 + kg * 8;
        f32x4 v0 = *(const f32x4*)(Arow + k0);
        f32x4 v1 = *(const f32x4*)(Arow + k0 + 4);
        bf16x8 af;
        af[0] = f2bf(v0[0]); af[1] = f2bf(v0[1]);
        af[2] = f2bf(v0[2]); af[3] = f2bf(v0[3]);
        af[4] = f2bf(v1[0]); af[5] = f2bf(v1[1]);
        af[6] = f2bf(v1[2]); af[7] = f2bf(v1[3]);
        a[ks] = af;
    }
    f32x4 acc[NCB];
#pragma unroll
    for (int ns = 0; ns < NCB; ++ns) acc[ns] = (f32x4){0.f, 0.f, 0.f, 0.f};
    __syncthreads();
#pragma unroll
    for (int ks = 0; ks < 4; ++ks)
#pragma unroll
        for (int ns = 0; ns < NCB; ++ns) {
            int n = ns * 16 + r16;
            int byte = (n << 8) + (ks << 6) + (kg << 4);
            byte ^= (n & 7) << 4;
            bf16x8 b = *(const bf16x8*)((const char*)Bsf + byte);
            acc[ns] = __builtin_amdgcn_mfma_f32_16x16x32_bf16(a[ks], b, acc[ns], 0, 0, 0);
        }
    __syncthreads();
#pragma unroll
    for (int it = 0; it < 7; ++it) {
        int lbyte = (it * 256 + tid) << 4;
        int L = lbyte ^ (((lbyte >> 8) & 7) << 4);
        int srcoff = ((L >> 8) << 9) + (L & 255) + 256;
        gload16(Wcb + srcoff, (char*)Bsf + lbyte);
    }
    __syncthreads();
#pragma unroll
    for (int ks = 0; ks < 4; ++ks)
#pragma unroll
        for (int ns = 0; ns < NCB; ++ns) {
            int n = ns * 16 + r16;
            int byte = (n << 8) + (ks << 6) + (kg << 4);
            byte ^= (n & 7) << 4;
            bf16x8 b = *(const bf16x8*)((const char*)Bsf + byte);
            acc[ns] = __builtin_amdgcn_mfma_f32_16x16x32_bf16(a[4 + ks], b, acc[ns], 0, 0, 0);
        }
    const float* bg = megab + (size_t)g * DIM_OUT + (size_t)cb * BN;
    int rbase = wv * 16 + kg * 4;
    int orow[4];
#pragma unroll
    for (int j = 0; j < 4; ++j)
        orow[j] = (rbase + j < rc) ? idxlist[rbase + j] : -1;
#pragma unroll
    for (int ns = 0; ns < NCB; ++ns) {
        int nloc = ns * 16 + r16;
        float bias = bg[nloc];
#pragma unroll
        for (int j = 0; j < 4; ++j) {
            if (orow[j] >= 0) {
                float x = acc[ns][j] + bias;
                out[(size_t)orow[j] * DIM_OUT + cb * BN + nloc] = 1.0f / (1.0f + __expf(-x));
            }
        }
    }
}

extern "C" void kernel_launch(void* const* d_in, const int* in_sizes, int n_in,
                              void* d_out, int out_size, void* d_ws, size_t ws_size,
                              hipStream_t stream) {
    const float* theta = (const float*)d_in[0];
    const int*   label = (const int*)d_in[1];
    const float* megaW = (const float*)d_in[2];
    const float* megab = (const float*)d_in[3];
    float* out = (float*)d_out;
    int* wsi = (int*)d_ws;
    short* wbf = (short*)((char*)d_ws + WS_WBF_BYTES);

    prep_k    <<<1012, 256, 0, stream>>>(megaW, label, wsi, wbf);
    scatter2_k<<<32, 512, 0, stream>>>(label, wsi);

    if (ws_size >= (size_t)WS_NEED_NEW) {
        short* thsort = (short*)((char*)d_ws + WS_TH_BYTES);
        gth_k     <<<2048, 256, 0, stream>>>(theta, wsi, thsort);
        moe_gemm6_k<<<G6_BLOCKS, 256, 0, stream>>>(thsort, megab, wsi, wbf, out);
    } else {
        moe_gemm4_k<<<GEMM_BLOCKS, 256, 0, stream>>>(theta, megab, wsi, wbf, out);
    }
}

// Round 7
// 54.709 us; speedup vs baseline: 1.3592x; 1.3592x over previous
//
#include <hip/hip_runtime.h>
#include <hip/hip_bf16.h>

#define NDIGIT 10
#define DIM_IN 256
#define DIM_OUT 784
#define BATCH 16384
#define NCT 49                           // 784/16 col-tiles
#define MAX_CH32 (BATCH / 32 + NDIGIT)   // 522 worst-case 32-row chunks
#define G7_BLOCKS (MAX_CH32 * 2)         // 1044 (x2 col halves)

// ws layout:
//  ints [0..10]    bucket row offsets[11]
//  ints [40..50]   32-row chunk offsets[11]
//  ints [52]       total chunks
//  ints [64 + j*16 + g]  per-hist-block partial counts (j<32, g<10)
//  ints [1024..17407]    idx[16384]
//  byte 69632..           W bf16 FRAG-PACKED: [g][ct:49][ks:8][lane:64][8]
//                         = 10*49*8*64*8 shorts = 2,007,040 shorts
//  byte 4,083,712..       thsort bf16 (16384 x 256, sorted by label)
#define WS_IDX 1024
#define WS_WBF_BYTES 69632
#define WS_TH_BYTES (WS_WBF_BYTES + 2007040 * 2)   // 4,083,712

typedef __attribute__((ext_vector_type(4))) float f32x4;
typedef __attribute__((ext_vector_type(8))) short bf16x8;

__device__ __forceinline__ short f2bf(float f) {
    union { float f; unsigned u; } c; c.f = f;
    unsigned u = c.u;
    u += 0x7fffu + ((u >> 16) & 1u);   // RNE
    return (short)(u >> 16);
}

__device__ __forceinline__ void gload16(const void* gp, void* lp) {
    __builtin_amdgcn_global_load_lds(
        (const __attribute__((address_space(1))) void*)gp,
        (__attribute__((address_space(3))) void*)lp, 16, 0, 0);
}

// blocks [0,980): pack megaW f32 -> bf16 in MFMA-fragment order
//   thread idx = b*256+t: gi=idx>>9 (g*49+ct), ks=(idx>>6)&7, l=idx&63
//   holds B elems for col=ct*16+(l&15), k=ks*32+(l>>4)*8+j (j=0..7)
// blocks [980,1012): per-512-row label histograms
__global__ void prep_k(const float* __restrict__ megaW,
                       const int* __restrict__ label,
                       int* __restrict__ wsi,
                       short* __restrict__ wbf) {
    int b = blockIdx.x, t = threadIdx.x;
    if (b < 980) {
        int idx = b * 256 + t;            // 0..250879 = 490*8*64
        int gi = idx >> 9;                // g*49 + ct
        int ks = (idx >> 6) & 7;
        int l  = idx & 63;
        int g  = gi / 49;
        int ct = gi - g * 49;
        int col = ct * 16 + (l & 15);
        int k   = ks * 32 + ((l >> 4) << 3);
        const float* src = megaW + ((size_t)(g * DIM_OUT + col) * DIM_IN + k);
        f32x4 v0 = *(const f32x4*)src;
        f32x4 v1 = *(const f32x4*)(src + 4);
        bf16x8 o;
        o[0] = f2bf(v0[0]); o[1] = f2bf(v0[1]); o[2] = f2bf(v0[2]); o[3] = f2bf(v0[3]);
        o[4] = f2bf(v1[0]); o[5] = f2bf(v1[1]); o[6] = f2bf(v1[2]); o[7] = f2bf(v1[3]);
        *(bf16x8*)(wbf + (size_t)idx * 8) = o;
    } else {
        __shared__ int h[NDIGIT];
        int j = b - 980;
        if (t < NDIGIT) h[t] = 0;
        __syncthreads();
        int i0 = j * 512;
        atomicAdd(&h[label[i0 + t]], 1);
        atomicAdd(&h[label[i0 + 256 + t]], 1);
        __syncthreads();
        if (t < NDIGIT) wsi[64 + j * 16 + t] = h[t];
    }
}

// 32 blocks x 512 threads; block j owns rows [j*512, j*512+512)
__global__ void scatter2_k(const int* __restrict__ label, int* __restrict__ wsi) {
    __shared__ int tot[NDIGIT], bef[NDIGIT], base[NDIGIT + 1], cur[NDIGIT];
    int j = blockIdx.x, t = threadIdx.x;
    if (t < NDIGIT) {
        int s = 0, sb = 0;
        for (int jj = 0; jj < 32; ++jj) {
            int v = wsi[64 + jj * 16 + t];
            s += v;
            if (jj < j) sb += v;
        }
        tot[t] = s; bef[t] = sb;
    }
    __syncthreads();
    if (t == 0) {
        int off = 0;
        for (int g = 0; g < NDIGIT; ++g) { base[g] = off; off += tot[g]; }
        base[NDIGIT] = off;
    }
    __syncthreads();
    if (t < NDIGIT) cur[t] = base[t] + bef[t];
    __syncthreads();
    int i = j * 512 + t;
    int g = label[i];
    int r = atomicAdd(&cur[g], 1);
    wsi[WS_IDX + r] = i;
    if (j == 0 && t == 0) {
        int off = 0, c32 = 0;
        for (int g2 = 0; g2 < NDIGIT; ++g2) {
            wsi[g2] = off;
            wsi[40 + g2] = c32;
            off += tot[g2];
            c32 += (tot[g2] + 31) / 32;
        }
        wsi[10] = off;
        wsi[50] = c32;
        wsi[52] = c32;
    }
}

// gather theta rows into sorted order, converted to bf16
__global__ void gth_k(const float* __restrict__ theta,
                      const int* __restrict__ wsi,
                      short* __restrict__ thsort) {
    int gid = blockIdx.x * 256 + threadIdx.x;
    int r = gid >> 5;
    int c8 = (gid & 31) << 3;
    int src = wsi[WS_IDX + r];
    const float* p = theta + (size_t)src * DIM_IN + c8;
    f32x4 v0 = *(const f32x4*)p;
    f32x4 v1 = *(const f32x4*)(p + 4);
    bf16x8 o;
    o[0] = f2bf(v0[0]); o[1] = f2bf(v0[1]); o[2] = f2bf(v0[2]); o[3] = f2bf(v0[3]);
    o[4] = f2bf(v1[0]); o[5] = f2bf(v1[1]); o[6] = f2bf(v1[2]); o[7] = f2bf(v1[3]);
    *(bf16x8*)(thsort + (size_t)r * DIM_IN + c8) = o;
}

// gemm7: 32 sorted rows x half the col-tiles per block. A staged to LDS once
// (one barrier), hoisted to 64 VGPRs; B streamed frag-packed from L2
// (perfectly coalesced); no steady-state LDS/barriers; 16 waves/CU.
__launch_bounds__(256, 4)
__global__ void moe_gemm7_k(const short* __restrict__ thsort,
                            const float* __restrict__ megab,
                            const int* __restrict__ wsi,
                            const short* __restrict__ wbf,
                            float* __restrict__ out) {
    __shared__ char As[16384];          // 32 rows x 512 B, XOR-swizzled

    int Bid = blockIdx.x;
    const int q8 = G7_BLOCKS / 8, r8 = G7_BLOCKS % 8;   // 130, 4
    int xcd = Bid & 7, slot = Bid >> 3;
    int w = (xcd < r8 ? xcd * (q8 + 1) : r8 * (q8 + 1) + (xcd - r8) * q8) + slot;
    int ch = w >> 1, half = w & 1;

    int total = wsi[52];
    if (ch >= total) return;            // uniform exit before the barrier

    int tid = threadIdx.x;
    int wv = tid >> 6, l = tid & 63, r16 = l & 15, kg = l >> 4;

    // expert mapping via one ballot (no dependent-load walk)
    int coff = (l < 11) ? wsi[40 + l] : 0x7fffffff;
    int boff = (l < 11) ? wsi[l] : 0;
    unsigned long long m = __ballot(ch >= coff);
    int g = __popcll(m) - 1;
    int lc    = ch - __shfl(coff, g);
    int start = __shfl(boff, g);
    int cnt   = __shfl(boff, g + 1) - start;
    int row0  = lc * 32;
    int rc    = min(32, cnt - row0);

    // ---- stage A chunk (32 rows x 512 B) : linear LDS dest, pre-swizzled src
#pragma unroll
    for (int it = 0; it < 4; ++it) {
        int lbyte = (it * 256 + tid) << 4;
        int L = lbyte ^ (((lbyte >> 9) & 7) << 4);   // involution
        int srow = L >> 9, koff = L & 511;
        int grow = row0 + srow;
        if (grow > cnt - 1) grow = cnt - 1;          // clamp (dup row, stores masked)
        gload16((const char*)thsort + (((size_t)(start + grow)) << 9) + koff,
                As + lbyte);
    }

    // output rows for this lane (C layout: col=l&15, row=kg*4+j per 16-row sub)
    const int* idxl = wsi + WS_IDX + start + row0;
    int orow[8];
#pragma unroll
    for (int ms = 0; ms < 2; ++ms)
#pragma unroll
        for (int j = 0; j < 4; ++j) {
            int rl = ms * 16 + kg * 4 + j;
            orow[ms * 4 + j] = (rl < rc) ? idxl[rl] : -1;
        }

    __syncthreads();                    // A staged (single barrier)

    // ---- hoist A fragments: a[ms][ks], row = ms*16 + r16
    bf16x8 a[2][8];
#pragma unroll
    for (int ms = 0; ms < 2; ++ms)
#pragma unroll
        for (int ks = 0; ks < 8; ++ks) {
            int row = ms * 16 + r16;
            int byte = (row << 9) + (ks << 6) + (kg << 4);
            byte ^= (row & 7) << 4;
            a[ms][ks] = *(const bf16x8*)(As + byte);
        }

    // ---- col-tile loop: B frag-packed from L2, 16 MFMA per tile
    const short* Wg = wbf + (size_t)g * (NCT * 4096);   // 4096 shorts per ct
    const float* bgb = megab + (size_t)g * DIM_OUT;

    int ctend = half ? NCT : 25;
    for (int ct = half * 25 + wv; ct < ctend; ct += 4) {
        const short* Bt = Wg + (size_t)ct * 4096 + l * 8;
        float bias = bgb[ct * 16 + r16];
        f32x4 acc0 = {0.f, 0.f, 0.f, 0.f}, acc1 = {0.f, 0.f, 0.f, 0.f};
#pragma unroll
        for (int ks = 0; ks < 8; ++ks) {
            bf16x8 b = *(const bf16x8*)(Bt + ks * 512);
            acc0 = __builtin_amdgcn_mfma_f32_16x16x32_bf16(a[0][ks], b, acc0, 0, 0, 0);
            acc1 = __builtin_amdgcn_mfma_f32_16x16x32_bf16(a[1][ks], b, acc1, 0, 0, 0);
        }
        int colb = ct * 16 + r16;
#pragma unroll
        for (int j = 0; j < 4; ++j) {
            if (orow[j] >= 0) {
                float x = acc0[j] + bias;
                out[(size_t)orow[j] * DIM_OUT + colb] = 1.0f / (1.0f + __expf(-x));
            }
            if (orow[4 + j] >= 0) {
                float x = acc1[j] + bias;
                out[(size_t)orow[4 + j] * DIM_OUT + colb] = 1.0f / (1.0f + __expf(-x));
            }
        }
    }
}

extern "C" void kernel_launch(void* const* d_in, const int* in_sizes, int n_in,
                              void* d_out, int out_size, void* d_ws, size_t ws_size,
                              hipStream_t stream) {
    const float* theta = (const float*)d_in[0];
    const int*   label = (const int*)d_in[1];
    const float* megaW = (const float*)d_in[2];
    const float* megab = (const float*)d_in[3];
    float* out = (float*)d_out;
    int* wsi = (int*)d_ws;
    short* wbf = (short*)((char*)d_ws + WS_WBF_BYTES);
    short* thsort = (short*)((char*)d_ws + WS_TH_BYTES);

    prep_k    <<<1012, 256, 0, stream>>>(megaW, label, wsi, wbf);
    scatter2_k<<<32, 512, 0, stream>>>(label, wsi);
    gth_k     <<<2048, 256, 0, stream>>>(theta, wsi, thsort);
    moe_gemm7_k<<<G7_BLOCKS, 256, 0, stream>>>(thsort, megab, wsi, wbf, out);
}